// Round 8
// baseline (58.520 us; speedup 1.0000x reference)
//
#include <hip/hip_runtime.h>

__device__ __forceinline__ float frcp(float x) { return __builtin_amdgcn_rcpf(x); }

// ---------------- Kernel A: level-1, register-resident recurrences ----------------
// Block = (mode, b, window-pair wp). wx computed with W1 in SGPRs (uniform scalar
// loads), staged once to LDS; recurrence fully in registers (U1/bg1 in SGPRs).
__global__ __launch_bounds__(256) void l1_kernel(
    const float* __restrict__ inp, const float* __restrict__ W1,
    const float* __restrict__ U1, const float* __restrict__ bg1,
    const float* __restrict__ bu1, const float* __restrict__ zeta1,
    const float* __restrict__ nu1, float* __restrict__ hrowg,
    float* __restrict__ hcolg) {
  constexpr int ST = 97;  // odd stride: scalar reads 2-way-free across 64 lanes
  __shared__ float wxs[112 * ST];  // 43.5 KB

  const int tid = threadIdx.x;
  const int bid = blockIdx.x;
  const bool isrow = bid < 448;
  const int v = isrow ? bid : bid - 448;
  const int b = v / 14, wp = v % 14;
  const int base4 = 8 * wp;
  const int span = (wp == 13) ? 8 : 12;

  // ---- wx phase: per-thread up to 6 pixels; W1 from uniform scalar loads ----
  int qk[6], sk[6];
  const float* pk[6];
  bool actk[6];
#pragma unroll
  for (int k = 0; k < 6; ++k) {
    const int p = tid + 256 * k;
    int q, s;
    if (isrow) { q = p / 12;  s = p - 12 * q; }
    else       { q = p % 112; s = p / 112; }
    qk[k] = q; sk[k] = s;
    actk[k] = (p < 1344) && (s < span);
    pk[k] = isrow
        ? inp + ((size_t)(b * 112 + q) * 112 + base4 + s) * 16
        : inp + ((size_t)(b * 112 + base4 + s) * 112 + q) * 16;
  }

  float acc[6][8];
#pragma unroll
  for (int k = 0; k < 6; ++k)
#pragma unroll
    for (int j = 0; j < 8; ++j) acc[k][j] = 0.f;

#pragma unroll 1
  for (int half = 0; half < 2; ++half) {
    const float* w1h = W1 + half * 64;  // rows half*8 .. half*8+7 (uniform)
#pragma unroll
    for (int k = 0; k < 6; ++k) {
      if (actk[k]) {
        const float4* xp = (const float4*)(pk[k] + half * 8);
        float4 x0 = xp[0], x1 = xp[1];
        float xr[8] = {x0.x, x0.y, x0.z, x0.w, x1.x, x1.y, x1.z, x1.w};
#pragma unroll
        for (int ci = 0; ci < 8; ++ci)
#pragma unroll
          for (int j = 0; j < 8; ++j)
            acc[k][j] = fmaf(xr[ci], w1h[ci * 8 + j], acc[k][j]);
      }
    }
  }

#pragma unroll
  for (int k = 0; k < 6; ++k)
    if (actk[k]) {
      float* wd = &wxs[qk[k] * ST + sk[k] * 8];
#pragma unroll
      for (int j = 0; j < 8; ++j) wd[j] = acc[k][j];
    }

  // ---- uniform recurrence weights (scalar loads -> SGPRs) ----
  float u1r[8][8];
#pragma unroll
  for (int i = 0; i < 8; ++i)
#pragma unroll
    for (int j = 0; j < 8; ++j) u1r[i][j] = U1[i * 8 + j];
  float bgv[8], Kc[8];
#pragma unroll
  for (int j = 0; j < 8; ++j) {
    bgv[j] = bg1[j];
    Kc[j] = __expf(2.f * (bg1[j] - bu1[j]));
  }
  const float zg = frcp(1.f + __expf(-zeta1[0]));
  const float ng = frcp(1.f + __expf(-nu1[0]));
  const float A = zg + ng;

  __syncthreads();

  // ---- recurrence: lane = (wl, r), fully register-resident ----
  const int nact = (wp == 13) ? 112 : 224;
  if (tid < nact) {
    const int wl = tid / 112, r = tid - 112 * wl;
    const int base = r * ST + wl * 32;
    float h[8];
    {  // t = 0 (h == 0)
#pragma unroll
      for (int j = 0; j < 8; ++j) {
        float s = __expf(-(wxs[base + j] + bgv[j]));
        float z = frcp(1.f + s);
        float u = s * s * Kc[j];
        float c = fmaf(2.f, frcp(1.f + u), -1.f);
        float m = fmaf(-zg, z, A);
        h[j] = m * c;
      }
    }
#pragma unroll
    for (int t = 1; t < 8; ++t) {
      float qa[8];
#pragma unroll
      for (int j = 0; j < 8; ++j) {
        float q = u1r[0][j] * h[0];
        q = fmaf(u1r[1][j], h[1], q);
        q = fmaf(u1r[2][j], h[2], q);
        q = fmaf(u1r[3][j], h[3], q);
        q = fmaf(u1r[4][j], h[4], q);
        q = fmaf(u1r[5][j], h[5], q);
        q = fmaf(u1r[6][j], h[6], q);
        q = fmaf(u1r[7][j], h[7], q);
        qa[j] = q;
      }
#pragma unroll
      for (int j = 0; j < 8; ++j) {
        float pre = wxs[base + t * 8 + j] + qa[j];
        float s = __expf(-(pre + bgv[j]));
        float z = frcp(1.f + s);
        float u = s * s * Kc[j];
        float c = fmaf(2.f, frcp(1.f + u), -1.f);
        float m = fmaf(-zg, z, A);
        h[j] = fmaf(z, h[j], m * c);
      }
    }
    float* dst = (isrow ? hrowg : hcolg) +
                 ((size_t)(b * 27 + 2 * wp + wl) * 112 + r) * 8;
    ((float4*)dst)[0] = float4{h[0], h[1], h[2], h[3]};
    ((float4*)dst)[1] = float4{h[4], h[5], h[6], h[7]};
  }
}

// ---------------- Kernel B: level-2, one lane per branch-recurrence ----------------
// Wave = 16 patches x 4 branches. h2[16] in VGPRs; U2/W2 via uniform scalar loads
// (re-fetched per step; asm clobber blocks hoisting); h rows direct from global.
// Zero LDS, zero barriers, zero cross-lane.
__global__ __launch_bounds__(64) void l2_kernel(
    const float* __restrict__ hrowg, const float* __restrict__ hcolg,
    const float* __restrict__ W2, const float* __restrict__ U2,
    const float* __restrict__ bg2, const float* __restrict__ bu2,
    const float* __restrict__ zeta2, const float* __restrict__ nu2,
    float* __restrict__ out) {
  const int lane = threadIdx.x;
  const int p = lane >> 2, g = lane & 3;
  const int n = blockIdx.x * 16 + p;
  const int pw = n % 27;
  const int q = n / 27;
  const int ph = q % 27, b = q / 27;
  const int rev = g & 1;

  const float* hs = (g < 2)
      ? &hrowg[((size_t)(b * 27 + pw) * 112 + ph * 4) * 8]
      : &hcolg[((size_t)(b * 27 + ph) * 112 + pw * 4) * 8];

  float bgv[16], Kc[16];
#pragma unroll
  for (int j = 0; j < 16; ++j) {
    bgv[j] = bg2[j];
    Kc[j] = __expf(2.f * (bg2[j] - bu2[j]));
  }
  const float zg = frcp(1.f + __expf(-zeta2[0]));
  const float ng = frcp(1.f + __expf(-nu2[0]));
  const float A = zg + ng;

  float h2[16];
#pragma unroll
  for (int j = 0; j < 16; ++j) h2[j] = 0.f;

  float cur[8], nxt[8];
  {
    const float4* rp = (const float4*)(hs + (rev ? 7 : 0) * 8);
    float4 r0 = rp[0], r1 = rp[1];
    cur[0] = r0.x; cur[1] = r0.y; cur[2] = r0.z; cur[3] = r0.w;
    cur[4] = r1.x; cur[5] = r1.y; cur[6] = r1.z; cur[7] = r1.w;
  }

#pragma unroll 1
  for (int t = 0; t < 8; ++t) {
    asm volatile("" ::: "memory");  // block LICM of the 384 weight loads
    if (t < 7) {
      const int tt2 = rev ? (6 - t) : (t + 1);
      const float4* rp = (const float4*)(hs + tt2 * 8);
      float4 r0 = rp[0], r1 = rp[1];
      nxt[0] = r0.x; nxt[1] = r0.y; nxt[2] = r0.z; nxt[3] = r0.w;
      nxt[4] = r1.x; nxt[5] = r1.y; nxt[6] = r1.z; nxt[7] = r1.w;
    }
    float pre[16];
#pragma unroll
    for (int j = 0; j < 16; ++j) pre[j] = cur[0] * W2[j];
#pragma unroll
    for (int d = 1; d < 8; ++d)
#pragma unroll
      for (int j = 0; j < 16; ++j)
        pre[j] = fmaf(cur[d], W2[d * 16 + j], pre[j]);
    if (t > 0) {
#pragma unroll
      for (int i = 0; i < 16; ++i)
#pragma unroll
        for (int j = 0; j < 16; ++j)
          pre[j] = fmaf(h2[i], U2[i * 16 + j], pre[j]);
    }
#pragma unroll
    for (int j = 0; j < 16; ++j) {
      float s = __expf(-(pre[j] + bgv[j]));
      float z = frcp(1.f + s);
      float u = s * s * Kc[j];
      float c = fmaf(2.f, frcp(1.f + u), -1.f);
      float m = fmaf(-zg, z, A);
      h2[j] = fmaf(z, h2[j], m * c);
    }
    if (t < 7) {
#pragma unroll
      for (int d = 0; d < 8; ++d) cur[d] = nxt[d];
    }
  }

  float* op = out + (size_t)n * 64 + g * 16;
  ((float4*)op)[0] = float4{h2[0], h2[1], h2[2], h2[3]};
  ((float4*)op)[1] = float4{h2[4], h2[5], h2[6], h2[7]};
  ((float4*)op)[2] = float4{h2[8], h2[9], h2[10], h2[11]};
  ((float4*)op)[3] = float4{h2[12], h2[13], h2[14], h2[15]};
}

extern "C" void kernel_launch(void* const* d_in, const int* in_sizes, int n_in,
                              void* d_out, int out_size, void* d_ws, size_t ws_size,
                              hipStream_t stream) {
  const float* inp   = (const float*)d_in[0];
  const float* W1    = (const float*)d_in[1];
  const float* U1    = (const float*)d_in[2];
  const float* bg1   = (const float*)d_in[3];
  const float* bu1   = (const float*)d_in[4];
  const float* zeta1 = (const float*)d_in[5];
  const float* nu1   = (const float*)d_in[6];
  const float* W2    = (const float*)d_in[7];
  const float* U2    = (const float*)d_in[8];
  const float* bg2   = (const float*)d_in[9];
  const float* bu2   = (const float*)d_in[10];
  const float* zeta2 = (const float*)d_in[11];
  const float* nu2   = (const float*)d_in[12];
  float* out = (float*)d_out;

  const size_t HSZ = (size_t)32 * 27 * 112 * 8;  // floats per h buffer
  float* hrowg = (float*)d_ws;
  float* hcolg = hrowg + HSZ;

  // Kernel A: 2 modes x 32 b x 14 window-pairs = 896 blocks
  l1_kernel<<<dim3(896), dim3(256), 0, stream>>>(
      inp, W1, U1, bg1, bu1, zeta1, nu1, hrowg, hcolg);
  // Kernel B: 23328 patches x 4 branches = 93312 lanes = 1458 single-wave blocks
  l2_kernel<<<dim3(1458), dim3(64), 0, stream>>>(
      hrowg, hcolg, W2, U2, bg2, bu2, zeta2, nu2, out);
}